// Round 7
// baseline (99.098 us; speedup 1.0000x reference)
//
#include <hip/hip_runtime.h>
#include <math.h>

#define NDIRS 64
#define NBIN 65
#define WIN 21                 // slots/lane: pair-span <= 18.48 -> ceil span <= 19, +1
#define WROW (WIN*64)          // 1344 floats per wave window
#define STAGEF 512             // 64 cells * 8 aggregates per wave (f32)
#define THREADS 512
#define WPB 8
#define SPW 2                  // paired strips (i,j),(i,j+1), j even
#define NBLK 256               // 256*8*2 = 4096 strips
#define ROWF (NDIRS*NBIN)      // 4160 (bins 0..64 x 64 dirs, bin-major)
#define NROWS 256              // partial rows (one per block)

static constexpr float INV = 0.28867513459481287f; // 1/(2*sqrt(3))

__global__ __launch_bounds__(THREADS) void wect_hist(
    const float* __restrict__ x, const float* __restrict__ dirs,
    float* __restrict__ accum) {
  __shared__ float histw[WPB * WROW];     // 43,008 B (windowed, bin-major)
  __shared__ float stage[WPB * STAGEF];   // 16,384 B
  __shared__ int   b0s[WPB * 64];         //  2,048 B  (61.4 KB total)
  const int tid = threadIdx.x;
  const int lane = tid & 63;
  const int wid  = tid >> 6;

  float4* h4 = (float4*)histw;
  for (int idx = tid; idx < WPB * WROW / 4; idx += THREADS)
    h4[idx] = make_float4(0.f, 0.f, 0.f, 0.f);
  __syncthreads();

  // lane = DIRECTION constants (pre-scaled by 1/dh)
  const float D0 = dirs[3*lane+0] * INV;
  const float D1 = dirs[3*lane+1] * INV;
  const float D2 = dirs[3*lane+2] * INV;
  const float Q1 = fmaxf(D0, 0.f);
  const float Q2 = fmaxf(D1, 0.f);
  const float Q3 = fmaxf(D2, 0.f);
  const float Q4 = Q2 + Q3;
  const float Q5 = Q1 + Q3;
  const float Q6 = Q1 + Q2;
  const float Q7 = Q1 + Q2 + Q3;

  // windowed hist, bin-major: addr = slot*64 + lane -> bank = lane%32
  // (2-way = free), independent of slot: conflict-free RMW.
  float* __restrict__ myhw = histw + wid * WROW + lane;
  float4* __restrict__ mystage = (float4*)(stage + wid * STAGEF);

  // Shared window for the strip pair: u spans width <= 63|D2| + |D1| <= 18.48
  // -> ceil(hi)-ceil(lo) <= 19 -> slot w in [0,19], w+1 <= 20 < WIN.
  const int strip0 = (blockIdx.x * WPB + wid) * SPW;   // even -> j0 even
  const int i = strip0 >> 6, j0 = strip0 & 63;         // pair never crosses i
  const float u00 = (float)i * D0 + (float)j0 * D1;
  const float u01 = u00 + D1;
  const float e00 = fmaf(63.f, D2, u00);
  const float e01 = fmaf(63.f, D2, u01);
  const int wbase = (int)ceilf(fminf(fminf(u00, e00), fminf(u01, e01)));
  b0s[wid*64 + lane] = wbase + 32;          // global bin of slot 0

  for (int s = 0; s < SPW; ++s) {
    const int strip = strip0 + s;
    const int j = j0 + s;
    const int l = lane;                       // lane = CELL for load phase
    const float* p = x + (strip << 6) + l;
    const int dL = (l < 63) ? 1 : 0;
    const int dJ = (j < 63) ? 64 : 0;
    const int dI = (i < 63) ? 4096 : 0;
    const bool iv = dI != 0, jv = dJ != 0, lv = dL != 0;

    const float x000 = p[0],       x001 = p[dL];
    const float x010 = p[dJ],      x011 = p[dJ+dL];
    const float x100 = p[dI],      x101 = p[dI+dL];
    const float x110 = p[dI+dJ],   x111 = p[dI+dJ+dL];

    const float e0m = fmaxf(x000, x100);
    const float e1m = fmaxf(x000, x010);
    const float e2m = fmaxf(x000, x001);
    const float s12 = fmaxf(fmaxf(e1m, x001), x011);
    const float s02 = fmaxf(fmaxf(e0m, x001), x101);
    const float s01 = fmaxf(fmaxf(e0m, x010), x110);
    const float cc  = fmaxf(fmaxf(s01, fmaxf(x001, x101)), fmaxf(x011, x111));

    const float v1 = iv ? -e0m : 0.f;
    const float v2 = jv ? -e1m : 0.f;
    const float v3 = lv ? -e2m : 0.f;
    const float v4 = (jv && lv) ? s12 : 0.f;
    const float v5 = (iv && lv) ? s02 : 0.f;
    const float v6 = (iv && jv) ? s01 : 0.f;
    const float v7 = (iv && jv && lv) ? -cc : 0.f;
    const float T  = x000 + v1+v2+v3+v4+v5+v6+v7;

    // stage this wave's 64 cells' aggregates: 2x ds_write_b128 per lane.
    // Same-wave DS ops are in-order: s=1 writes can't pass s=0's reads.
    mystage[2*lane]     = make_float4(T,  v1, v2, v3);
    mystage[2*lane + 1] = make_float4(v4, v5, v6, v7);

    const float u0 = (s == 0) ? u00 : u01;    // per-lane(dir)

    // R6's proven RMW inner loop, byte-identical (shared wbase).
    #pragma unroll 8
    for (int t = 0; t < 64; ++t) {
      const float4 A = mystage[2*t];      // T, v1, v2, v3 (same-addr broadcast)
      const float4 B = mystage[2*t + 1];  // v4, v5, v6, v7
      const float u  = fmaf((float)t, D2, u0);
      const float bf = ceilf(u);
      const float fr = bf - u;                 // [0,1)
      const int   w  = (int)bf - wbase;        // slot in [0,19]
      float S = 0.f;
      S += (Q1 > fr) ? A.y : 0.f;
      S += (Q2 > fr) ? A.z : 0.f;
      S += (Q3 > fr) ? A.w : 0.f;
      S += (Q4 > fr) ? B.x : 0.f;
      S += (Q5 > fr) ? B.y : 0.f;
      S += (Q6 > fr) ? B.z : 0.f;
      S += (Q7 > fr) ? B.w : 0.f;
      float* a = myhw + (w << 6);              // bank = lane%32, conflict-free
      const float r0 = a[0], r1 = a[64];       // ds_read2 (+64 dwords)
      a[0]  = r0 + (A.x - S);
      a[64] = r1 + S;                          // slot w+1 <= 20
    }
  }

  __syncthreads();
  // epilogue: map each wave's 21-slot window into the block's 65x64 row.
  // k = tid&63 constant per thread -> window bases hoisted; bank = k%32.
  float* __restrict__ obase = accum + blockIdx.x * ROWF;
  const int k = tid & 63;
  const int b0 = b0s[0*64 + k], b1 = b0s[1*64 + k],
            b2 = b0s[2*64 + k], b3 = b0s[3*64 + k],
            b4 = b0s[4*64 + k], b5 = b0s[5*64 + k],
            b6 = b0s[6*64 + k], b7 = b0s[7*64 + k];
  for (int z = tid; z < ROWF; z += THREADS) {
    const int c = z >> 6;                      // global bin 0..64
    float v = 0.f;
    int w;
    w = c - b0; if ((unsigned)w < WIN) v += histw[0*WROW + (w << 6) + k];
    w = c - b1; if ((unsigned)w < WIN) v += histw[1*WROW + (w << 6) + k];
    w = c - b2; if ((unsigned)w < WIN) v += histw[2*WROW + (w << 6) + k];
    w = c - b3; if ((unsigned)w < WIN) v += histw[3*WROW + (w << 6) + k];
    w = c - b4; if ((unsigned)w < WIN) v += histw[4*WROW + (w << 6) + k];
    w = c - b5; if ((unsigned)w < WIN) v += histw[5*WROW + (w << 6) + k];
    w = c - b6; if ((unsigned)w < WIN) v += histw[6*WROW + (w << 6) + k];
    w = c - b7; if ((unsigned)w < WIN) v += histw[7*WROW + (w << 6) + k];
    obase[z] = v;                              // guard bin 65 never read
  }
}

// fused reduce(256 rows)+scan: block k = dir; accum is L2/L3-resident (4.3 MB)
__global__ __launch_bounds__(512) void wect_scan(
    const float* __restrict__ accum, float* __restrict__ out) {
  __shared__ float red[8 * NBIN];
  __shared__ float s[NBIN];
  const int k = blockIdx.x, tid = threadIdx.x;
  // accum bin-major: element (row r, bin c, dir k) = accum[r*ROWF + c*64 + k]
  for (int z = tid; z < 8 * NBIN; z += 512) {   // 520 items > 512 thr: stride
    const int g = z / NBIN, c = z - g * NBIN;
    float v = 0.f;
    #pragma unroll 4
    for (int r = g; r < NROWS; r += 8) v += accum[r * ROWF + (c << 6) + k];
    red[z] = v;
  }
  __syncthreads();
  if (tid < NBIN) {
    float v = 0.f;
    #pragma unroll
    for (int gg = 0; gg < 8; ++gg) v += red[gg * NBIN + tid];
    s[tid] = v;
  }
  __syncthreads();
  for (int off = 1; off < NBIN; off <<= 1) {
    float a = 0.f;
    if (tid < NBIN && tid >= off) a = s[tid - off];
    __syncthreads();
    if (tid < NBIN && tid >= off) s[tid] += a;
    __syncthreads();
  }
  if (tid < NBIN) out[k * NBIN + tid] = s[tid];
}

extern "C" void kernel_launch(void* const* d_in, const int* in_sizes, int n_in,
                              void* d_out, int out_size, void* d_ws, size_t ws_size,
                              hipStream_t stream) {
  const float* x = (const float*)d_in[0];
  const float* dirs = (const float*)d_in[1];
  float* out = (float*)d_out;
  float* accum = (float*)d_ws;                 // 256*4160 floats = 4.26 MB

  wect_hist<<<NBLK, THREADS, 0, stream>>>(x, dirs, accum);
  wect_scan<<<NDIRS, 512, 0, stream>>>(accum, out);
}

// Round 8
// 84.828 us; speedup vs baseline: 1.1682x; 1.1682x over previous
//
#include <hip/hip_runtime.h>
#include <math.h>

#define NDIRS 64
#define NBIN 65
#define WIN 21                 // window slots/lane: bin span <=20 incl. +1 slot
#define WROW (WIN*64)          // 1344 floats per wave window
#define STAGEF 512             // 64 cells * 8 aggregates per wave (f32)
#define THREADS 512
#define WPB 8
#define NBLK 512               // 512*8 = 4096 strips, ONE per wave
#define ROWF (NDIRS*NBIN)      // 4160 (= bins 0..64 x 64 dirs, bin-major)

static constexpr float INV = 0.28867513459481287f; // 1/(2*sqrt(3))

__global__ __launch_bounds__(THREADS) void wect_hist(
    const float* __restrict__ x, const float* __restrict__ dirs,
    float* __restrict__ accum) {
  __shared__ float histw[WPB * WROW];     // 43,008 B (windowed, bin-major)
  __shared__ float stage[WPB * STAGEF];   // 16,384 B
  __shared__ int   b0s[WPB * 64];         //  2,048 B  (60 KB -> 2 blk/CU,
  const int tid = threadIdx.x;            //   16 waves/CU = 4/SIMD)
  const int lane = tid & 63;
  const int wid  = tid >> 6;

  float4* h4 = (float4*)histw;
  for (int idx = tid; idx < WPB * WROW / 4; idx += THREADS)
    h4[idx] = make_float4(0.f, 0.f, 0.f, 0.f);
  __syncthreads();

  // lane = DIRECTION constants (pre-scaled by 1/dh)
  const float D0 = dirs[3*lane+0] * INV;
  const float D1 = dirs[3*lane+1] * INV;
  const float D2 = dirs[3*lane+2] * INV;
  const float Q1 = fmaxf(D0, 0.f);
  const float Q2 = fmaxf(D1, 0.f);
  const float Q3 = fmaxf(D2, 0.f);
  const float Q4 = Q2 + Q3;
  const float Q5 = Q1 + Q3;
  const float Q6 = Q1 + Q2;
  const float Q7 = Q1 + Q2 + Q3;

  // windowed hist, bin-major: addr = slot*64 + lane -> bank = lane%32
  // (2-way = free), independent of slot: conflict-free RMW.
  float* __restrict__ myhw = histw + wid * WROW + lane;
  float4* __restrict__ mystage = (float4*)(stage + wid * STAGEF);

  {
    const int strip = blockIdx.x * WPB + wid;   // [0,4096), ONE per wave
    const int i = strip >> 6, j = strip & 63;
    const int l = lane;                       // lane = CELL for load phase
    const float* p = x + (strip << 6) + l;
    const int dL = (l < 63) ? 1 : 0;
    const int dJ = (j < 63) ? 64 : 0;
    const int dI = (i < 63) ? 4096 : 0;
    const bool iv = dI != 0, jv = dJ != 0, lv = dL != 0;

    const float x000 = p[0],       x001 = p[dL];
    const float x010 = p[dJ],      x011 = p[dJ+dL];
    const float x100 = p[dI],      x101 = p[dI+dL];
    const float x110 = p[dI+dJ],   x111 = p[dI+dJ+dL];

    const float e0m = fmaxf(x000, x100);
    const float e1m = fmaxf(x000, x010);
    const float e2m = fmaxf(x000, x001);
    const float s12 = fmaxf(fmaxf(e1m, x001), x011);
    const float s02 = fmaxf(fmaxf(e0m, x001), x101);
    const float s01 = fmaxf(fmaxf(e0m, x010), x110);
    const float cc  = fmaxf(fmaxf(s01, fmaxf(x001, x101)), fmaxf(x011, x111));

    const float v1 = iv ? -e0m : 0.f;
    const float v2 = jv ? -e1m : 0.f;
    const float v3 = lv ? -e2m : 0.f;
    const float v4 = (jv && lv) ? s12 : 0.f;
    const float v5 = (iv && lv) ? s02 : 0.f;
    const float v6 = (iv && jv) ? s01 : 0.f;
    const float v7 = (iv && jv && lv) ? -cc : 0.f;
    const float T  = x000 + v1+v2+v3+v4+v5+v6+v7;

    // stage this wave's 64 cells' aggregates: 2x ds_write_b128 per lane
    mystage[2*lane]     = make_float4(T,  v1, v2, v3);
    mystage[2*lane + 1] = make_float4(v4, v5, v6, v7);

    const float u0 = (float)i * D0 + (float)j * D1;   // per-lane(dir)

    // Window: ib(t) = ceil(u0 + t*D2) is monotone in t, span <= 19, so
    // slot w = ib - wbase with wbase = min(ib(0), ib(63)) lies in [0,19];
    // r1 goes to w+1 <= 20. WIN=21 slots replace the 66-bin row.
    const float u63 = fmaf(63.f, D2, u0);
    const int ib0  = (int)ceilf(u0);
    const int ib63 = (int)ceilf(u63);
    const int wbase = min(ib0, ib63);
    b0s[wid*64 + lane] = wbase + 32;          // global bin of slot 0

    #pragma unroll 8
    for (int t = 0; t < 64; ++t) {
      const float4 A = mystage[2*t];      // T, v1, v2, v3 (same-addr broadcast)
      const float4 B = mystage[2*t + 1];  // v4, v5, v6, v7
      const float u  = fmaf((float)t, D2, u0);
      const float bf = ceilf(u);
      const float fr = bf - u;                 // [0,1)
      const int   w  = (int)bf - wbase;        // slot in [0,19]
      float S = 0.f;
      S += (Q1 > fr) ? A.y : 0.f;
      S += (Q2 > fr) ? A.z : 0.f;
      S += (Q3 > fr) ? A.w : 0.f;
      S += (Q4 > fr) ? B.x : 0.f;
      S += (Q5 > fr) ? B.y : 0.f;
      S += (Q6 > fr) ? B.z : 0.f;
      S += (Q7 > fr) ? B.w : 0.f;
      float* a = myhw + (w << 6);              // bank = lane%32, conflict-free
      const float r0 = a[0], r1 = a[64];       // ds_read2 (+64 dwords)
      a[0]  = r0 + (A.x - S);
      a[64] = r1 + S;                          // slot w+1 <= 20
    }
  }

  __syncthreads();
  // epilogue: map each wave's 21-slot window into the block's 65x64 row.
  float* __restrict__ obase = accum + blockIdx.x * ROWF;
  const int k = tid & 63;
  const int b0 = b0s[0*64 + k], b1 = b0s[1*64 + k],
            b2 = b0s[2*64 + k], b3 = b0s[3*64 + k],
            b4 = b0s[4*64 + k], b5 = b0s[5*64 + k],
            b6 = b0s[6*64 + k], b7 = b0s[7*64 + k];
  for (int z = tid; z < ROWF; z += THREADS) {
    const int c = z >> 6;                      // global bin 0..64
    float v = 0.f;
    int w;
    w = c - b0; if ((unsigned)w < WIN) v += histw[0*WROW + (w << 6) + k];
    w = c - b1; if ((unsigned)w < WIN) v += histw[1*WROW + (w << 6) + k];
    w = c - b2; if ((unsigned)w < WIN) v += histw[2*WROW + (w << 6) + k];
    w = c - b3; if ((unsigned)w < WIN) v += histw[3*WROW + (w << 6) + k];
    w = c - b4; if ((unsigned)w < WIN) v += histw[4*WROW + (w << 6) + k];
    w = c - b5; if ((unsigned)w < WIN) v += histw[5*WROW + (w << 6) + k];
    w = c - b6; if ((unsigned)w < WIN) v += histw[6*WROW + (w << 6) + k];
    w = c - b7; if ((unsigned)w < WIN) v += histw[7*WROW + (w << 6) + k];
    obase[z] = v;                              // guard bin 65 never read
  }
}

// 65 blocks, one per bin c. lane = dir -> every load is a contiguous 256B
// segment (fully coalesced). Reads accum exactly once (8.5 MB), no gather.
__global__ __launch_bounds__(512) void wect_colsum(
    const float* __restrict__ accum, float* __restrict__ cs) {
  __shared__ float part[8 * 64];
  const int c = blockIdx.x;                  // 0..64
  const int k = threadIdx.x & 63;            // dir
  const int w = threadIdx.x >> 6;            // wave 0..7
  const float* __restrict__ base = accum + (c << 6) + k;
  float acc = 0.f;
  #pragma unroll 8
  for (int m = 0; m < NBLK / 8; ++m)         // rows w, w+8, ..., w+504
    acc += base[(w + (m << 3)) * ROWF];
  part[(w << 6) + k] = acc;
  __syncthreads();
  if (w == 0) {
    float t = 0.f;
    #pragma unroll
    for (int g = 0; g < 8; ++g) t += part[(g << 6) + k];
    cs[(c << 6) + k] = t;                    // colsum[c][k]
  }
}

// inclusive prefix over bins per dir. cs is 16.6 KB (L2-hot); lane = dir ->
// coalesced 256B loads; 65 serial fp-adds per lane; scattered stores trivial.
__global__ __launch_bounds__(64) void wect_scan(
    const float* __restrict__ cs, float* __restrict__ out) {
  const int k = threadIdx.x;                 // dir
  float s = 0.f;
  #pragma unroll 5
  for (int c = 0; c < NBIN; ++c) {
    s += cs[(c << 6) + k];
    out[k * NBIN + c] = s;
  }
}

extern "C" void kernel_launch(void* const* d_in, const int* in_sizes, int n_in,
                              void* d_out, int out_size, void* d_ws, size_t ws_size,
                              hipStream_t stream) {
  const float* x = (const float*)d_in[0];
  const float* dirs = (const float*)d_in[1];
  float* out = (float*)d_out;
  float* accum = (float*)d_ws;                 // 512*4160 floats = 8.5 MB
  float* cs = accum + NBLK * ROWF;             // 65*64 floats = 16.6 KB

  wect_hist<<<NBLK, THREADS, 0, stream>>>(x, dirs, accum);
  wect_colsum<<<NBIN, 512, 0, stream>>>(accum, cs);
  wect_scan<<<1, 64, 0, stream>>>(cs, out);
}